// Round 8
// baseline (237.623 us; speedup 1.0000x reference)
//
#include <hip/hip_runtime.h>

#define BATCH 128
#define NPTS  4096
#define EPT   8                    // owned cells per thread
#define W     16                   // per-thread window: 4 halo + 8 owned + 4 halo
#define WREG  (64 * EPT)           // 512-cell region per wave
#define HALOC 104                  // wave-halo >= 99 steps contamination (group-quantized: cell>=104 safe)
#define OWN   (WREG - 2 * HALOC)   // 304 owned cells per interior wave
#define SEGS  14                   // ceil(4096/304); edge segs clamp to domain
#define TPB   64                   // one independent wave per block

// Halved-coefficient flux: g(u) = 0.5*f(u), ah(u) = 0.5*|f'(u)|
// f  = 1.5u + 0.75b u^2 + (-0.5-2b) u^3 + 1.5b u^4 - 0.25b u^6,  b = beta/12
// f' = 1.5 + 1.5b u - (1.5+6b) u^2 + 6b u^3 - 1.5b u^5
__device__ __forceinline__ void flux_eval(float u, float& g, float& ah) {
    constexpr float b  = 0.1f / 12.0f;
    constexpr float c6 = 0.5f * (-0.25f * b);
    constexpr float c4 = 0.5f * ( 1.5f  * b);
    constexpr float c3 = 0.5f * (-0.5f - 2.0f * b);
    constexpr float c2 = 0.5f * ( 0.75f * b);
    constexpr float c1 = 0.5f * ( 1.5f);
    constexpr float d5 = 0.5f * (-1.5f * b);
    constexpr float d3 = 0.5f * ( 6.0f * b);
    constexpr float d2 = 0.5f * (-(1.5f + 6.0f * b));
    constexpr float d1 = 0.5f * ( 1.5f * b);
    constexpr float d0 = 0.5f * ( 1.5f);

    float t = c6 * u;            // c5 == 0
    t = fmaf(t, u, c4);
    t = fmaf(t, u, c3);
    t = fmaf(t, u, c2);
    t = fmaf(t, u, c1);
    g = u * t;

    float e = d5 * u;            // d4 == 0
    e = fmaf(e, u, d3);
    e = fmaf(e, u, d2);
    e = fmaf(e, u, d1);
    e = fmaf(e, u, d0);
    ah = fabsf(e);
}

// One in-window step at tile depth J: updates cells [J, 15-J] from states
// [J-1, 16-J]. All indices compile-time -> pure registers (no scratch).
template<int J>
__device__ __forceinline__ void stepJ(float (&w)[W], const bool bcL, const bool bcR) {
    constexpr int LO = J;
    constexpr int HI = 15 - J;
    constexpr int NS = HI - LO + 3;          // states LO-1 .. HI+1
    float g[NS], a[NS];
#pragma unroll
    for (int i = 0; i < NS; ++i) flux_eval(w[LO - 1 + i], g[i], a[i]);
    float fh[NS - 1];                        // interface m: between states LO-1+m, LO+m
#pragma unroll
    for (int m = 0; m < NS - 1; ++m)
        fh[m] = g[m] + g[m + 1] - fmaxf(a[m], a[m + 1]) * (w[LO + m] - w[LO - 1 + m]);
#pragma unroll
    for (int i = LO; i <= HI; ++i)           // r = DT/DX = 0.5 exactly
        w[i] = fmaf(-0.5f, fh[i - LO + 1] - fh[i - LO], w[i]);
    if (bcL) w[4] = w[5];                    // cell 0   <- cell 1   (every step)
    if (bcR) w[11] = w[10];                  // cell N-1 <- cell N-2
}

// Refill halos: w[0..3] <- left lane's owned top, w[12..15] <- right lane's
// owned bottom. Read set {4..11} disjoint from write set -> safe in place.
// Lane 0 / lane 63 self-copies produce garbage halos; wave-level HALOC (or the
// BC at domain edges) absorbs the resulting 1-cell/step contamination.
__device__ __forceinline__ void exchange(float (&w)[W]) {
    w[0]  = __shfl_up(w[8],  1, 64);
    w[1]  = __shfl_up(w[9],  1, 64);
    w[2]  = __shfl_up(w[10], 1, 64);
    w[3]  = __shfl_up(w[11], 1, 64);
    w[12] = __shfl_down(w[4], 1, 64);
    w[13] = __shfl_down(w[5], 1, 64);
    w[14] = __shfl_down(w[6], 1, 64);
    w[15] = __shfl_down(w[7], 1, 64);
}

__device__ __forceinline__ void st_owned(float* p, const float (&w)[W]) {
    *(float4*)p       = make_float4(w[4], w[5], w[6], w[7]);
    *(float4*)(p + 4) = make_float4(w[8], w[9], w[10], w[11]);
}

__global__ __launch_bounds__(TPB) void pde_timetile(
        const float* __restrict__ init,
        const int*   __restrict__ stepnum_p,
        float*       __restrict__ out) {
    const int wid  = blockIdx.x;
    const int lane = threadIdx.x;
    const int row  = wid / SEGS;
    const int seg  = wid - row * SEGS;

    const int ownlo = seg * OWN;                       // 0, 304, ..., 3952
    const int base  = min(max(ownlo - HALOC, 0), NPTS - WREG);
    const int c0    = base + lane * EPT;               // first owned cell of this thread
    const bool ownstore = (c0 >= ownlo) && (c0 < ownlo + OWN);
    const bool bcL = (seg == 0) && (lane == 0);        // owns cell 0
    const bool bcR = (seg == SEGS - 1) && (lane == 63);// owns cell N-1
    const int stepnum = *stepnum_p;

    // Window load: cells c0-4 .. c0+11 as four float4s; OOB chunks (domain-edge
    // lanes only) clamp to valid addresses -> finite garbage in BC-protected slots.
    const float* ip = init + (size_t)row * NPTS;
    const int o0 = max(c0 - 4, 0);
    const int o3 = min(c0 + 8, NPTS - 4);
    const float4 L0 = *(const float4*)(ip + o0);
    const float4 L1 = *(const float4*)(ip + c0);
    const float4 L2 = *(const float4*)(ip + c0 + 4);
    const float4 L3 = *(const float4*)(ip + o3);
    float w[W] = {L0.x, L0.y, L0.z, L0.w, L1.x, L1.y, L1.z, L1.w,
                  L2.x, L2.y, L2.z, L2.w, L3.x, L3.y, L3.z, L3.w};

    const size_t Z = (size_t)BATCH * NPTS;
    float* op = out + (size_t)row * NPTS + c0;

    if (ownstore) st_owned(op, w);                     // out[step=0] = init verbatim
    op += Z;                                           // plane s=1

    int s = 1;
    // 4 time steps per halo exchange: window shrinks 16->14->12->10 cells of
    // validity; owned w[4..11] stay exact at every intermediate level.
    for (; s + 4 <= stepnum; s += 4) {
        exchange(w);
        stepJ<1>(w, bcL, bcR); if (ownstore) st_owned(op,         w);
        stepJ<2>(w, bcL, bcR); if (ownstore) st_owned(op + Z,     w);
        stepJ<3>(w, bcL, bcR); if (ownstore) st_owned(op + 2 * Z, w);
        stepJ<4>(w, bcL, bcR); if (ownstore) st_owned(op + 3 * Z, w);
        op += 4 * Z;
    }
    const int k = stepnum - s;                         // 0..3 remaining steps
    if (k > 0) {
        exchange(w);
        stepJ<1>(w, bcL, bcR); if (ownstore) st_owned(op, w);
        if (k > 1) { stepJ<2>(w, bcL, bcR); if (ownstore) st_owned(op + Z, w); }
        if (k > 2) { stepJ<3>(w, bcL, bcR); if (ownstore) st_owned(op + 2 * Z, w); }
    }
}

extern "C" void kernel_launch(void* const* d_in, const int* in_sizes, int n_in,
                              void* d_out, int out_size, void* d_ws, size_t ws_size,
                              hipStream_t stream) {
    const float* init  = (const float*)d_in[0];
    const int*   steps = (const int*)d_in[1];
    float*       out   = (float*)d_out;
    pde_timetile<<<BATCH * SEGS, TPB, 0, stream>>>(init, steps, out);
}